// Round 1
// baseline (375.603 us; speedup 1.0000x reference)
//
#include <hip/hip_runtime.h>
#include <math.h>

#define EPSF 1e-5f

__device__ __forceinline__ float tanhf_fast(float x) {
    return 1.f - 2.f / (__expf(2.f * x) + 1.f);
}

// ---------------------------------------------------------------------------
// Kernel 1: the two 64-input MLPs (blockIdx 0 = block/bd, 1 = freq/fd)
// ---------------------------------------------------------------------------
__device__ void mlp64_body(const float* __restrict__ xin,   // 32 rows, stride 128, 64 cols
                           const float* __restrict__ Win,   // 64x128
                           const float* __restrict__ bin_,  // 128
                           const float* __restrict__ Wmid,  // 2x128x128
                           const float* __restrict__ bmid,  // 2x128
                           const float* __restrict__ Wout,  // 128x36
                           const float* __restrict__ bout,  // 36
                           const float* __restrict__ gamma, // 3x128
                           const float* __restrict__ beta,  // 3x128
                           float* __restrict__ out)         // 32x36
{
    __shared__ float sX[32 * 64];
    __shared__ float sA[32 * 128];
    __shared__ float sB[32 * 128];
    __shared__ float sMu[128], sRs[128];
    int tid = threadIdx.x;

    for (int idx = tid; idx < 32 * 64; idx += 256) {
        int b = idx >> 6, c = idx & 63;
        sX[idx] = xin[b * 128 + c];
    }
    __syncthreads();

    // layer 1: (32,64) @ (64,128)
    for (int idx = tid; idx < 32 * 128; idx += 256) {
        int b = idx >> 7, j = idx & 127;
        float acc = bin_[j];
        for (int c = 0; c < 64; ++c) acc = fmaf(sX[b * 64 + c], Win[c * 128 + j], acc);
        sA[idx] = fmaxf(acc, 0.f);
    }
    __syncthreads();

    float* cur = sA;
    float* nxt = sB;
    for (int l = 0; l < 3; ++l) {
        if (tid < 128) {
            float s = 0.f, s2 = 0.f;
            for (int b = 0; b < 32; ++b) {
                float v = cur[b * 128 + tid];
                s += v; s2 += v * v;
            }
            float mu = s * (1.f / 32.f);
            float var = s2 * (1.f / 32.f) - mu * mu;
            sMu[tid] = mu;
            sRs[tid] = rsqrtf(var + EPSF);
        }
        __syncthreads();
        for (int idx = tid; idx < 32 * 128; idx += 256) {
            int j = idx & 127;
            cur[idx] = gamma[l * 128 + j] * (cur[idx] - sMu[j]) * sRs[j] + beta[l * 128 + j];
        }
        __syncthreads();
        if (l < 2) {
            for (int idx = tid; idx < 32 * 128; idx += 256) {
                int b = idx >> 7, j = idx & 127;
                float acc = bmid[l * 128 + j];
                for (int c = 0; c < 128; ++c)
                    acc = fmaf(cur[b * 128 + c], Wmid[(l * 128 + c) * 128 + j], acc);
                nxt[idx] = fmaxf(acc, 0.f);
            }
            __syncthreads();
            float* t = cur; cur = nxt; nxt = t;
        } else {
            for (int idx = tid; idx < 32 * 36; idx += 256) {
                int b = idx / 36, j = idx - b * 36;
                float acc = bout[j];
                for (int c = 0; c < 128; ++c)
                    acc = fmaf(cur[b * 128 + c], Wout[c * 36 + j], acc);
                out[idx] = fmaxf(acc, 0.f);
            }
        }
    }
}

__global__ __launch_bounds__(256) void k_mlp2(
    const float* __restrict__ x,
    const float* fdWin, const float* fdbin, const float* fdWmid, const float* fdbmid,
    const float* fdWout, const float* fdbout, const float* fdg, const float* fdbt,
    const float* bdWin, const float* bdbin, const float* bdWmid, const float* bdbmid,
    const float* bdWout, const float* bdbout, const float* bdg, const float* bdbt,
    float* freq, float* blk)
{
    if (blockIdx.x == 0)
        mlp64_body(x + 64, bdWin, bdbin, bdWmid, bdbmid, bdWout, bdbout, bdg, bdbt, blk);
    else
        mlp64_body(x, fdWin, fdbin, fdWmid, fdbmid, fdWout, fdbout, fdg, fdbt, freq);
}

// ---------------------------------------------------------------------------
// Kernel 2: 36 per-s MLPs (input scalar per sample) -> cos -> fseq[t][b][s]
// ---------------------------------------------------------------------------
__global__ __launch_bounds__(512) void k_sc(
    const float* __restrict__ freq,  // 32x36
    const float* __restrict__ Win,   // 36x1x128
    const float* __restrict__ bin_,  // 36x128
    const float* __restrict__ Wmid,  // 36x2x128x128
    const float* __restrict__ bmid,  // 36x2x128
    const float* __restrict__ Wout,  // 36x128x256
    const float* __restrict__ bout,  // 36x256
    const float* __restrict__ gamma, // 36x3x128
    const float* __restrict__ beta,  // 36x3x128
    float* __restrict__ fseq)        // 256 x 32 x 36
{
    int s = blockIdx.x, tid = threadIdx.x;
    __shared__ float sA[32 * 128];
    __shared__ float sB[32 * 128];
    __shared__ float sMu[128], sRs[128];
    const float* Wm = Wmid + (size_t)s * 2 * 128 * 128;
    const float* Wo = Wout + (size_t)s * 128 * 256;
    const float* gm = gamma + s * 3 * 128;
    const float* bt = beta + s * 3 * 128;

    for (int idx = tid; idx < 32 * 128; idx += 512) {
        int b = idx >> 7, j = idx & 127;
        float acc = fmaf(freq[b * 36 + s], Win[s * 128 + j], bin_[s * 128 + j]);
        sA[idx] = fmaxf(acc, 0.f);
    }
    __syncthreads();

    float* cur = sA;
    float* nxt = sB;
    for (int l = 0; l < 3; ++l) {
        if (tid < 128) {
            float sm = 0.f, s2 = 0.f;
            for (int b = 0; b < 32; ++b) {
                float v = cur[b * 128 + tid];
                sm += v; s2 += v * v;
            }
            float mu = sm * (1.f / 32.f);
            float var = s2 * (1.f / 32.f) - mu * mu;
            sMu[tid] = mu;
            sRs[tid] = rsqrtf(var + EPSF);
        }
        __syncthreads();
        for (int idx = tid; idx < 32 * 128; idx += 512) {
            int j = idx & 127;
            cur[idx] = gm[l * 128 + j] * (cur[idx] - sMu[j]) * sRs[j] + bt[l * 128 + j];
        }
        __syncthreads();
        if (l < 2) {
            for (int idx = tid; idx < 32 * 128; idx += 512) {
                int b = idx >> 7, j = idx & 127;
                float acc = bmid[(s * 2 + l) * 128 + j];
                for (int c = 0; c < 128; ++c)
                    acc = fmaf(cur[b * 128 + c], Wm[(l * 128 + c) * 128 + j], acc);
                nxt[idx] = fmaxf(acc, 0.f);
            }
            __syncthreads();
            float* t = cur; cur = nxt; nxt = t;
        } else {
            for (int idx = tid; idx < 32 * 256; idx += 512) {
                int b = idx >> 8, n = idx & 255;
                float acc = bout[s * 256 + n];
                for (int c = 0; c < 128; ++c)
                    acc = fmaf(cur[b * 128 + c], Wo[c * 256 + n], acc);
                float v = fmaxf(acc, 0.f);
                fseq[((size_t)n * 32 + b) * 36 + s] = cosf(v);
            }
        }
    }
}

// ---------------------------------------------------------------------------
// Kernel 3: precompute x-part of LSTM gates for all t:
//   Xg[t][b][j] = bih[j]+bhh[j] + sum_s fseq[t][b][s] * Wih[j][s]
// ---------------------------------------------------------------------------
__global__ __launch_bounds__(512) void k_xg(
    const float* __restrict__ fseq, const float* __restrict__ Wih,
    const float* __restrict__ bih, const float* __restrict__ bhh,
    float* __restrict__ Xg)
{
    int t = blockIdx.x, tid = threadIdx.x;
    __shared__ float sF[32 * 36];
    for (int idx = tid; idx < 1152; idx += 512) sF[idx] = fseq[(size_t)t * 1152 + idx];
    __syncthreads();
    for (int idx = tid; idx < 32 * 144; idx += 512) {
        int b = idx / 144, j = idx - b * 144;
        float acc = bih[j] + bhh[j];
        #pragma unroll
        for (int s2 = 0; s2 < 36; ++s2)
            acc = fmaf(sF[b * 36 + s2], Wih[j * 36 + s2], acc);
        Xg[((size_t)t * 32 + b) * 144 + j] = acc;
    }
}

// ---------------------------------------------------------------------------
// Kernel 4: LSTM recurrence, one workgroup per batch sample
// ---------------------------------------------------------------------------
__global__ __launch_bounds__(192) void k_lstm(
    const float* __restrict__ Xg, const float* __restrict__ blockIn,
    const float* __restrict__ Whh, float* __restrict__ hseq)
{
    int b = blockIdx.x, tid = threadIdx.x;
    __shared__ float sh[36];
    __shared__ float sg[144];
    float w[36];
    if (tid < 144) {
        #pragma unroll
        for (int k = 0; k < 36; ++k) w[k] = Whh[tid * 36 + k];
    }
    if (tid < 36) sh[tid] = blockIn[b * 36 + tid];
    float c = 0.f;
    float xg = (tid < 144) ? Xg[(size_t)b * 144 + tid] : 0.f;
    const int type = tid / 36;
    __syncthreads();

    for (int t = 0; t < 256; ++t) {
        float act = 0.f;
        if (tid < 144) {
            float a0 = 0.f, a1 = 0.f, a2 = 0.f, a3 = 0.f;
            #pragma unroll
            for (int k = 0; k < 36; k += 4) {
                a0 = fmaf(w[k + 0], sh[k + 0], a0);
                a1 = fmaf(w[k + 1], sh[k + 1], a1);
                a2 = fmaf(w[k + 2], sh[k + 2], a2);
                a3 = fmaf(w[k + 3], sh[k + 3], a3);
            }
            float gate = xg + (a0 + a1) + (a2 + a3);
            float sarg = (type == 2) ? 2.f * gate : gate;
            float sv = 1.f / (1.f + __expf(-sarg));
            act = (type == 2) ? 2.f * sv - 1.f : sv;   // tanh(x)=2*sig(2x)-1
        }
        if (t < 255 && tid < 144) xg = Xg[((size_t)(t + 1) * 32 + b) * 144 + tid];
        if (tid < 144) sg[tid] = act;
        __syncthreads();
        if (tid < 36) {
            float iv = sg[tid], fv = sg[36 + tid], gv = sg[72 + tid], ov = sg[108 + tid];
            c = fmaf(fv, c, iv * gv);
            float h = ov * tanhf_fast(c);
            sh[tid] = h;
            hseq[((size_t)b * 256 + t) * 36 + tid] = h;
        }
        __syncthreads();
    }
}

// ---------------------------------------------------------------------------
// Kernel 5: mixed[b][o][n] = mix_b[o] + W[o,:36].block[b] + W[o,36:].hseq[b,n]
// ---------------------------------------------------------------------------
__global__ __launch_bounds__(256) void k_mixed(
    const float* __restrict__ blockIn, const float* __restrict__ hseq,
    const float* __restrict__ mixW, const float* __restrict__ mixb,
    float* __restrict__ mixed)
{
    int wg = blockIdx.x;  // b*36 + o
    int b = wg / 36, o = wg - b * 36;
    int n = threadIdx.x;
    float acc = mixb[o];
    const float* wrow = mixW + o * 72;
    const float* blk = blockIn + b * 36;
    #pragma unroll
    for (int c = 0; c < 36; ++c) acc = fmaf(wrow[c], blk[c], acc);
    const float* hp = hseq + ((size_t)b * 256 + n) * 36;
    #pragma unroll
    for (int u = 0; u < 36; ++u) acc = fmaf(wrow[36 + u], hp[u], acc);
    mixed[(size_t)wg * 256 + n] = acc;
}

// ---------------------------------------------------------------------------
// Kernel 6: assemble block-tridiagonal output (writes all 268 MB)
// ---------------------------------------------------------------------------
__device__ __forceinline__ float pauliv(int p, int r, int c) {
    switch (p) {
        case 0: return (r == c) ? 1.f : 0.f;
        case 1: return (r != c) ? 1.f : 0.f;
        case 2: return (r == 0 && c == 1) ? 1.f : ((r == 1 && c == 0) ? -1.f : 0.f);
        default: return (r == c) ? ((r == 0) ? 1.f : -1.f) : 0.f;
    }
}

__global__ __launch_bounds__(256) void k_asm(
    const float* __restrict__ mixed, float* __restrict__ out)
{
    int wg = blockIdx.x;  // (b*2+g)*256 + n
    int n = wg & 255, bg = wg >> 8;
    int g = bg & 1, b = bg >> 1;
    int tid = threadIdx.x;
    __shared__ float sD[16];
    __shared__ float sEdge[2];
    if (tid < 16) {
        int r = tid >> 2, c = tid & 3;
        float acc = 0.f;
        #pragma unroll
        for (int k = 0; k < 16; ++k) {
            float kv = pauliv(k >> 2, r >> 1, c >> 1) * pauliv(k & 3, r & 1, c & 1);
            acc = fmaf(mixed[((size_t)b * 36 + 4 + 16 * g + k) * 256 + n], kv, acc);
        }
        sD[tid] = acc;
    } else if (tid == 16) {
        sEdge[0] = mixed[((size_t)b * 36 + g) * 256 + n];        // subdiagonal scalar
    } else if (tid == 17) {
        sEdge[1] = mixed[((size_t)b * 36 + 2 + g) * 256 + n];    // superdiagonal scalar
    }
    __syncthreads();

    float4* outp = (float4*)out + ((size_t)bg * 1024 + 4 * n) * 256;
    int m = tid;
    if (m == n) {
        #pragma unroll
        for (int r = 0; r < 4; ++r)
            outp[r * 256 + m] = make_float4(sD[r * 4 + 0], sD[r * 4 + 1], sD[r * 4 + 2], sD[r * 4 + 3]);
    } else if (m == n - 1) {
        float v = sEdge[0];
        outp[0 * 256 + m] = make_float4(v, 0.f, 0.f, 0.f);
        outp[1 * 256 + m] = make_float4(0.f, v, 0.f, 0.f);
        outp[2 * 256 + m] = make_float4(0.f, 0.f, -v, 0.f);
        outp[3 * 256 + m] = make_float4(0.f, 0.f, 0.f, -v);
    } else if (m == n + 1) {
        float v = sEdge[1];
        outp[0 * 256 + m] = make_float4(v, 0.f, 0.f, 0.f);
        outp[1 * 256 + m] = make_float4(0.f, v, 0.f, 0.f);
        outp[2 * 256 + m] = make_float4(0.f, 0.f, -v, 0.f);
        outp[3 * 256 + m] = make_float4(0.f, 0.f, 0.f, -v);
    } else {
        float4 z = make_float4(0.f, 0.f, 0.f, 0.f);
        #pragma unroll
        for (int r = 0; r < 4; ++r) outp[r * 256 + m] = z;
    }
}

// ---------------------------------------------------------------------------
extern "C" void kernel_launch(void* const* d_in, const int* in_sizes, int n_in,
                              void* d_out, int out_size, void* d_ws, size_t ws_size,
                              hipStream_t stream) {
    const float* x      = (const float*)d_in[0];
    const float* fdWin  = (const float*)d_in[1];
    const float* fdbin  = (const float*)d_in[2];
    const float* fdWmid = (const float*)d_in[3];
    const float* fdbmid = (const float*)d_in[4];
    const float* fdWout = (const float*)d_in[5];
    const float* fdbout = (const float*)d_in[6];
    const float* fdg    = (const float*)d_in[7];
    const float* fdbt   = (const float*)d_in[8];
    const float* bdWin  = (const float*)d_in[9];
    const float* bdbin  = (const float*)d_in[10];
    const float* bdWmid = (const float*)d_in[11];
    const float* bdbmid = (const float*)d_in[12];
    const float* bdWout = (const float*)d_in[13];
    const float* bdbout = (const float*)d_in[14];
    const float* bdg    = (const float*)d_in[15];
    const float* bdbt   = (const float*)d_in[16];
    const float* scWin  = (const float*)d_in[17];
    const float* scbin  = (const float*)d_in[18];
    const float* scWmid = (const float*)d_in[19];
    const float* scbmid = (const float*)d_in[20];
    const float* scWout = (const float*)d_in[21];
    const float* scbout = (const float*)d_in[22];
    const float* scg    = (const float*)d_in[23];
    const float* scbt   = (const float*)d_in[24];
    const float* Wih    = (const float*)d_in[25];
    const float* Whh    = (const float*)d_in[26];
    const float* bih    = (const float*)d_in[27];
    const float* bhh    = (const float*)d_in[28];
    const float* mixW   = (const float*)d_in[29];
    const float* mixb   = (const float*)d_in[30];

    float* ws    = (float*)d_ws;
    float* freq  = ws;                 // 32*36      = 1152
    float* blk   = ws + 1152;          // 32*36      = 1152
    float* fseq  = ws + 2304;          // 256*32*36  = 294912
    float* Xg    = ws + 297216;        // 256*32*144 = 1179648
    float* hseq  = ws + 1476864;       // 32*256*36  = 294912
    float* mixed = ws + 1771776;       // 32*36*256  = 294912

    k_mlp2<<<2, 256, 0, stream>>>(x,
        fdWin, fdbin, fdWmid, fdbmid, fdWout, fdbout, fdg, fdbt,
        bdWin, bdbin, bdWmid, bdbmid, bdWout, bdbout, bdg, bdbt,
        freq, blk);
    k_sc<<<36, 512, 0, stream>>>(freq, scWin, scbin, scWmid, scbmid,
                                 scWout, scbout, scg, scbt, fseq);
    k_xg<<<256, 512, 0, stream>>>(fseq, Wih, bih, bhh, Xg);
    k_lstm<<<32, 192, 0, stream>>>(Xg, blk, Whh, hseq);
    k_mixed<<<1152, 256, 0, stream>>>(blk, hseq, mixW, mixb, mixed);
    k_asm<<<16384, 256, 0, stream>>>(mixed, (float*)d_out);
}